// Round 7
// baseline (121.221 us; speedup 1.0000x reference)
//
#include <hip/hip_runtime.h>

typedef __bf16 bf16;
typedef __bf16 bf16x4 __attribute__((ext_vector_type(4)));
typedef __bf16 bf16x8 __attribute__((ext_vector_type(8)));
typedef float  f32x4  __attribute__((ext_vector_type(4)));

#define CIN   256
#define KK    9
#define KDIM  2304
#define KITERS 72            // KDIM / 32
#define PXW   64             // pixels per WG

// force a wave-uniform value into an SGPR
__device__ __forceinline__ float sread(float f) {
    return __builtin_bit_cast(float,
        __builtin_amdgcn_readfirstlane(__builtin_bit_cast(int, f)));
}
__device__ __forceinline__ int sreadi(int v) {
    return __builtin_amdgcn_readfirstlane(v);
}

// ---------------------------------------------------------------------------
// Fused prep: blocks [0,1024) transpose x -> channels-last bf16 xt;
//             blocks [1024,3328) pack weight -> MFMA-fragment-ordered wq:
//   wq[ ((m*72 + kt)*64 + lane)*8 + j ] = W[o=m*16+l16][k=kt*32+quad*8+j]
//   k -> (tap = k>>8, c = k&255);  lane = quad*16+l16.
// ---------------------------------------------------------------------------
__global__ __launch_bounds__(256) void prep_k(const float* __restrict__ x,
                                              const float* __restrict__ w,
                                              bf16* __restrict__ xt,
                                              bf16* __restrict__ wq) {
    int bid = blockIdx.x;
    int tid = threadIdx.x;
    if (bid < 1024) {
        __shared__ bf16 tile[64][72];        // px-major; rows 144 B
        int pt = bid & 63, ct = (bid >> 6) & 3, b = bid >> 8;
        int lane = tid & 63, row = tid >> 6;
        const float* src = x + ((size_t)(b * 256 + ct * 64)) * 4096 + pt * 64;
        #pragma unroll
        for (int cc = row; cc < 64; cc += 4)
            tile[lane][cc] = (bf16)src[(size_t)cc * 4096 + lane];
        __syncthreads();
        bf16* dst = xt + ((size_t)(b * 4096 + pt * 64)) * 256 + ct * 64;
        int p = tid >> 3, j = tid & 7;
        #pragma unroll
        for (int pp = p; pp < 64; pp += 32)
            *reinterpret_cast<bf16x8*>(dst + (size_t)pp * 256 + j * 8) =
                *reinterpret_cast<const bf16x8*>(&tile[pp][j * 8]);
    } else {
        int idx  = (bid - 1024) * 256 + tid;   // < 589824
        int j    = idx & 7;
        int lane = (idx >> 3) & 63;
        int rest = idx >> 9;                   // m*72 + kt
        int kt   = rest % KITERS;
        int m    = rest / KITERS;
        int l16  = lane & 15;
        int quad = lane >> 4;
        int o    = m * 16 + l16;
        int k    = kt * 32 + quad * 8 + j;
        int tap  = k >> 8;
        int cc   = k & 255;
        wq[idx] = (bf16)w[(size_t)o * KDIM + cc * KK + tap];
    }
}

// ---------------------------------------------------------------------------
// Fused sampling -> LDS -> MFMA GEMM
// WG = 1024 thr (16 waves), 64 pixels. Wave = M16 (1 mtile) x N64 (4 ntiles)
// -> each weight element read ONCE per WG (weight L2 traffic halved vs N32).
// Grid 256 -> 1 WG/CU = 16 waves/CU (50% occupancy cap, same total waves).
// XCD band swizzle: bid&7 selects XCD; band = contiguous 2048 px, so each
// XCD's gathers (~1.1 MB) + weights (1.18 MB) live in its 4 MB L2
// (round-5 evidence: FETCH_SIZE 33.5 -> 10.3 MB).
// LDS S: XOR granule swizzle (granule g=16B at row n, col g stored at
// g ^ (n&7)). Writes: permutation within row -> 0 conflicts. Reads
// (b128): 2-way bank aliasing -> free (m136). Round-6 evidence for why:
// SROW=264 pad gave stride==4 mod 32 -> 8-way conflicts, 2.36M cycles.
// ---------------------------------------------------------------------------
__global__ __launch_bounds__(1024, 4) void deform_gemm_k(
    const bf16*  __restrict__ xt,
    const float* __restrict__ off,
    const bf16*  __restrict__ wq,
    const float* __restrict__ bias,
    float*       __restrict__ out) {

    __shared__ bf16 S[PXW * 256];   // 32,768 B, swizzled granules

    int tid   = threadIdx.x;
    int wavei = sreadi(tid >> 6);   // 0..15
    int lane  = tid & 63;
    int quad  = lane >> 4;
    int l16   = lane & 15;

    int bid   = blockIdx.x;                      // 0..255
    int pb    = ((bid & 7) << 5) | (bid >> 3);   // XCD-band pixel-block
    int pix0  = pb * PXW;
    int b     = pix0 >> 12;                      // WG-uniform batch
    int pimgb = pix0 & 4095;
    int obase = b * 73728;                       // scalar base into off[]
    unsigned base = (unsigned)b * 1048576u + (unsigned)(lane * 4); // into xt[]

    f32x4 acc[4];
    #pragma unroll
    for (int nt = 0; nt < 4; ++nt)
        acc[nt] = (f32x4){0.f, 0.f, 0.f, 0.f};

    int q3 = lane & 7;              // read-swizzle xor operand (l16&7 == lane&7)

    for (int tap = 0; tap < KK; ++tap) {
        int ty = tap / 3 - 1;
        int tx = tap % 3 - 1;

        // ---- sampling: wave fills rows n = wavei*4 .. wavei*4+3 ----
        int u[4][4];        // SGPR element offsets within batch image
        float wt[4][4];     // SGPR bilinear weights
        #pragma unroll
        for (int i = 0; i < 4; ++i) {
            int pimg = pimgb + wavei * 4 + i;              // scalar
            float oy = off[obase + pimg + (2 * tap) * 4096];      // s_load
            float ox = off[obase + pimg + (2 * tap + 1) * 4096];  // s_load
            float py = (float)((pimg >> 6) + ty) + oy;
            float px = (float)((pimg & 63) + tx) + ox;
            float fy = floorf(py), fx = floorf(px);
            int   y0 = (int)fy,    x0 = (int)fx;
            float wy1 = py - fy, wx1 = px - fx;
            float wy0 = 1.f - wy1, wx0 = 1.f - wx1;
            wy0 = ((unsigned)y0       < 64u) ? wy0 : 0.f;
            wy1 = ((unsigned)(y0 + 1) < 64u) ? wy1 : 0.f;
            wx0 = ((unsigned)x0       < 64u) ? wx0 : 0.f;
            wx1 = ((unsigned)(x0 + 1) < 64u) ? wx1 : 0.f;
            int yc0 = min(max(y0, 0), 63),     yc1 = min(max(y0 + 1, 0), 63);
            int xc0 = min(max(x0, 0), 63),     xc1 = min(max(x0 + 1, 0), 63);
            u[i][0] = sreadi((yc0 * 64 + xc0) * 256);
            u[i][1] = sreadi((yc0 * 64 + xc1) * 256);
            u[i][2] = sreadi((yc1 * 64 + xc0) * 256);
            u[i][3] = sreadi((yc1 * 64 + xc1) * 256);
            wt[i][0] = sread(wy0 * wx0); wt[i][1] = sread(wy0 * wx1);
            wt[i][2] = sread(wy1 * wx0); wt[i][3] = sread(wy1 * wx1);
        }
        // issue all 16 gathers back-to-back (L2-local after band swizzle)
        bf16x4 v[4][4];
        #pragma unroll
        for (int i = 0; i < 4; ++i)
            #pragma unroll
            for (int j = 0; j < 4; ++j)
                v[i][j] = *reinterpret_cast<const bf16x4*>(xt + base + (unsigned)u[i][j]);
        // blend + swizzled LDS write
        #pragma unroll
        for (int i = 0; i < 4; ++i) {
            float a0 = 0.f, a1 = 0.f, a2 = 0.f, a3 = 0.f;
            #pragma unroll
            for (int j = 0; j < 4; ++j) {
                float wgt = wt[i][j];
                a0 += wgt * (float)v[i][j][0];
                a1 += wgt * (float)v[i][j][1];
                a2 += wgt * (float)v[i][j][2];
                a3 += wgt * (float)v[i][j][3];
            }
            bf16x4 sv;
            sv[0] = (bf16)a0; sv[1] = (bf16)a1;
            sv[2] = (bf16)a2; sv[3] = (bf16)a3;
            int n   = wavei * 4 + i;
            int gsw = (lane >> 1) ^ (n & 7);                 // 16B-granule swizzle
            *reinterpret_cast<bf16x4*>(&S[n * 256 + gsw * 8 + (lane & 1) * 4]) = sv;
        }
        __syncthreads();

        // ---- GEMM over this tap's k=256: wave = mtile wavei, N64 ----
        const bf16* ap0 = wq + ((size_t)((wavei * KITERS + tap * 8) * 64 + lane)) * 8;
        #pragma unroll
        for (int kki = 0; kki < 8; ++kki) {
            bf16x8 a = *reinterpret_cast<const bf16x8*>(ap0 + (size_t)kki * 512);
            #pragma unroll
            for (int nt = 0; nt < 4; ++nt) {
                int row = nt * 16 + l16;
                int g   = (kki * 4 + quad) ^ q3;             // swizzled granule
                bf16x8 bb = *reinterpret_cast<const bf16x8*>(&S[row * 256 + g * 8]);
                acc[nt] = __builtin_amdgcn_mfma_f32_16x16x32_bf16(a, bb, acc[nt], 0, 0, 0);
            }
        }
        __syncthreads();   // S reused next tap
    }

    // ---- epilogue: C/D layout col=l16, row=quad*4+r; mtile = wavei ----
    #pragma unroll
    for (int nt = 0; nt < 4; ++nt) {
        int pg   = pix0 + nt * 16 + l16;
        int bb_  = pg >> 12;
        int pimg = pg & 4095;
        int m    = wavei * 16 + quad * 4;
        float* op = out + ((size_t)(bb_ * 256 + m)) * 4096 + pimg;
        #pragma unroll
        for (int r = 0; r < 4; ++r)
            op[(size_t)r * 4096] = acc[nt][r] + bias[m + r];
    }
}

// ---------------------------------------------------------------------------
extern "C" void kernel_launch(void* const* d_in, const int* in_sizes, int n_in,
                              void* d_out, int out_size, void* d_ws, size_t ws_size,
                              hipStream_t stream) {
    const float* x    = (const float*)d_in[0];   // [4,256,64,64]
    const float* off  = (const float*)d_in[1];   // [4,18,64,64]
    const float* w    = (const float*)d_in[2];   // [256,256,3,3]
    const float* bias = (const float*)d_in[3];   // [256]
    float* out = (float*)d_out;                  // [4,256,64,64]

    bf16* wq = (bf16*)d_ws;                               // 1,179,648 B
    bf16* xt = (bf16*)((char*)d_ws + (size_t)589824 * 2); // 8,388,608 B

    prep_k<<<3328, 256, 0, stream>>>(x, w, xt, wq);
    deform_gemm_k<<<256, 1024, 0, stream>>>(xt, off, wq, bias, out);
}